// Round 2
// baseline (901.366 us; speedup 1.0000x reference)
//
#include <hip/hip_runtime.h>
#include <hip/hip_bf16.h>
#include <cmath>

// Problem constants (from reference): N=100000, D=512, H1=16, C=40, NNZ=3.2M
#define DD 512
#define HH 16
#define CC 40

// ---------------------------------------------------------------------------
// K1: X1 = H @ W1   (N x 512) @ (512 x 16) -> (N x 16)
// One row per thread, 64-thread (1-wave) blocks for max block count.
// W1 reads are wave-uniform -> compiler scalarizes to s_load, SGPR FMA operand.
// H streamed via float4. HBM floor ~33us.
// ---------------------------------------------------------------------------
__global__ __launch_bounds__(64) void k_gemm1(const float* __restrict__ Hm,
                                              const float* __restrict__ W1,
                                              float* __restrict__ X1,
                                              int nrows) {
    int row = blockIdx.x * 64 + (int)threadIdx.x;
    if (row >= nrows) return;
    const float* hp = &Hm[(size_t)row * DD];
    const float4* w4 = reinterpret_cast<const float4*>(W1);  // [DD][4 x float4]

    float acc[HH];
#pragma unroll
    for (int j = 0; j < HH; ++j) acc[j] = 0.f;

    for (int k4 = 0; k4 < DD; k4 += 4) {
        float4 hv = *reinterpret_cast<const float4*>(hp + k4);
        float h[4] = {hv.x, hv.y, hv.z, hv.w};
#pragma unroll
        for (int kk = 0; kk < 4; ++kk) {
#pragma unroll
            for (int j4 = 0; j4 < 4; ++j4) {
                float4 w = w4[(k4 + kk) * 4 + j4];  // wave-uniform -> s_load
                acc[j4 * 4 + 0] += h[kk] * w.x;
                acc[j4 * 4 + 1] += h[kk] * w.y;
                acc[j4 * 4 + 2] += h[kk] * w.z;
                acc[j4 * 4 + 3] += h[kk] * w.w;
            }
        }
    }

    float4* op = reinterpret_cast<float4*>(&X1[(size_t)row * HH]);
#pragma unroll
    for (int j4 = 0; j4 < 4; ++j4)
        op[j4] = make_float4(acc[j4 * 4 + 0], acc[j4 * 4 + 1],
                             acc[j4 * 4 + 2], acc[j4 * 4 + 3]);
}

// ---------------------------------------------------------------------------
// CSR build (every call; no state may persist).
// ---------------------------------------------------------------------------
__global__ __launch_bounds__(256) void k_hist(const int* __restrict__ rows,
                                              int* __restrict__ cnt, int nnz) {
    int e = blockIdx.x * 256 + (int)threadIdx.x;
    if (e < nnz) atomicAdd(&cnt[rows[e]], 1);
}

// per-block inclusive scan (Hillis-Steele), block totals to bsum
__global__ __launch_bounds__(256) void k_scan1(const int* __restrict__ cnt,
                                               int* __restrict__ incl,
                                               int* __restrict__ bsum, int n) {
    __shared__ int s[256];
    int i = blockIdx.x * 256 + (int)threadIdx.x;
    int v = (i < n) ? cnt[i] : 0;
    s[threadIdx.x] = v;
    __syncthreads();
    for (int off = 1; off < 256; off <<= 1) {
        int add = (threadIdx.x >= (unsigned)off) ? s[threadIdx.x - off] : 0;
        __syncthreads();
        s[threadIdx.x] += add;
        __syncthreads();
    }
    if (i < n) incl[i] = s[threadIdx.x];
    if (threadIdx.x == 255) bsum[blockIdx.x] = s[255];
}

// single-block inclusive scan of block sums (n2 <= 512)
__global__ __launch_bounds__(512) void k_scan2(int* __restrict__ b, int n2) {
    __shared__ int s[512];
    int i = (int)threadIdx.x;
    s[i] = (i < n2) ? b[i] : 0;
    __syncthreads();
    for (int off = 1; off < 512; off <<= 1) {
        int add = (i >= off) ? s[i - off] : 0;
        __syncthreads();
        s[i] += add;
        __syncthreads();
    }
    if (i < n2) b[i] = s[i];
}

__global__ __launch_bounds__(256) void k_scan3(const int* __restrict__ incl,
                                               const int* __restrict__ bscan,
                                               const int* __restrict__ cnt,
                                               int* __restrict__ row_start,
                                               int* __restrict__ cursor, int n) {
    int i = blockIdx.x * 256 + (int)threadIdx.x;
    if (i >= n) return;
    int prev = (blockIdx.x > 0) ? bscan[blockIdx.x - 1] : 0;
    int inc = incl[i] + prev;          // inclusive prefix over all rows
    row_start[i + 1] = inc;
    cursor[i] = inc - cnt[i];          // exclusive (= row start)
    if (i == 0) row_start[0] = 0;
}

__global__ __launch_bounds__(256) void k_scatter(const int* __restrict__ rows,
                                                 const int* __restrict__ cols,
                                                 const float* __restrict__ vals,
                                                 int* __restrict__ cursor,
                                                 int* __restrict__ ecol,
                                                 float* __restrict__ eval, int nnz) {
    int e = blockIdx.x * 256 + (int)threadIdx.x;
    if (e >= nnz) return;
    int r = rows[e];
    int slot = atomicAdd(&cursor[r], 1);
    ecol[slot] = cols[e];
    eval[slot] = vals[e];
}

// ---------------------------------------------------------------------------
// Gather spmm: S[r][j] = sum_{i in row r} eval[i] * f(X[ecol[i]][j])
// thread per (row, feature). col/val reads wave-broadcast; no output atomics.
// ---------------------------------------------------------------------------
template <int RELU>
__global__ __launch_bounds__(256) void k_gather(const int* __restrict__ row_start,
                                                const int* __restrict__ ecol,
                                                const float* __restrict__ eval,
                                                const float* __restrict__ X,
                                                float* __restrict__ S,
                                                const float* __restrict__ bias,
                                                int nrows) {
    int t = blockIdx.x * 256 + (int)threadIdx.x;
    int r = t >> 4;
    int j = t & 15;
    if (r >= nrows) return;
    int s = row_start[r];
    int e = row_start[r + 1];
    float bj = RELU ? bias[j] : 0.f;
    float acc = 0.f;
    for (int i = s; i < e; ++i) {
        int c = ecol[i];
        float v = eval[i];
        float x = X[(size_t)c * HH + j];
        if (RELU) x = fmaxf(x + bj, 0.f);
        acc += v * x;
    }
    S[(size_t)r * HH + j] = acc;
}

// ---------------------------------------------------------------------------
// Fallback scatter spmm (if ws too small for CSR): thread per (edge, feature).
// ---------------------------------------------------------------------------
__global__ __launch_bounds__(256) void k_spmm(const int* __restrict__ rows,
                                              const int* __restrict__ cols,
                                              const float* __restrict__ vals,
                                              const float* __restrict__ X,
                                              float* __restrict__ S,
                                              const float* __restrict__ bias,
                                              int relu_in, int nnz) {
    long long idx = (long long)blockIdx.x * 256 + threadIdx.x;
    if (idx >= (long long)nnz * HH) return;
    int e = (int)(idx >> 4);
    int j = (int)(idx & 15);
    int c = cols[e];
    int r = rows[e];
    float v = vals[e];
    float x = X[(size_t)c * HH + j];
    if (relu_in) {
        x = fmaxf(x + bias[j], 0.f);
        if (x == 0.f) return;  // skip zero atomics
    }
    atomicAdd(&S[(size_t)r * HH + j], v * x);
}

// ---------------------------------------------------------------------------
// K4: out = log_softmax(relu(T @ W2 + b2)).  One thread per row.
// ---------------------------------------------------------------------------
__global__ __launch_bounds__(256) void k_out(const float* __restrict__ T,
                                             const float* __restrict__ W2,
                                             const float* __restrict__ b2,
                                             float* __restrict__ out,
                                             int nrows) {
    __shared__ float w2s[HH * CC];
    __shared__ float b2s[CC];
    for (int i = (int)threadIdx.x; i < HH * CC; i += 256) w2s[i] = W2[i];
    if (threadIdx.x < CC) b2s[threadIdx.x] = b2[threadIdx.x];
    __syncthreads();

    int row = blockIdx.x * 256 + (int)threadIdx.x;
    if (row >= nrows) return;

    float t[HH];
#pragma unroll
    for (int k4 = 0; k4 < HH; k4 += 4) {
        float4 tv = *reinterpret_cast<const float4*>(&T[(size_t)row * HH + k4]);
        t[k4] = tv.x; t[k4 + 1] = tv.y; t[k4 + 2] = tv.z; t[k4 + 3] = tv.w;
    }

    float y[CC];
#pragma unroll
    for (int j = 0; j < CC; ++j) {
        float a = b2s[j];
#pragma unroll
        for (int k = 0; k < HH; ++k) a += t[k] * w2s[k * CC + j];
        y[j] = a > 0.f ? a : 0.f;
    }

    float m = y[0];
#pragma unroll
    for (int j = 1; j < CC; ++j) m = fmaxf(m, y[j]);
    float s = 0.f;
#pragma unroll
    for (int j = 0; j < CC; ++j) s += __expf(y[j] - m);
    float ls = __logf(s) + m;

    float4* op = reinterpret_cast<float4*>(&out[(size_t)row * CC]);
#pragma unroll
    for (int j4 = 0; j4 < CC / 4; ++j4)
        op[j4] = make_float4(y[j4 * 4 + 0] - ls, y[j4 * 4 + 1] - ls,
                             y[j4 * 4 + 2] - ls, y[j4 * 4 + 3] - ls);
}

// ---------------------------------------------------------------------------
// Inputs (setup_inputs order):
//  0: H (N*512 f32)  1: A_vals (NNZ f32)  2: W1 (512*16)  3: b1 (16)
//  4: W2 (16*40)     5: b2 (40)           6: A_rows (NNZ i32) 7: A_cols (NNZ i32)
// Output: N*40 f32.
// ---------------------------------------------------------------------------
extern "C" void kernel_launch(void* const* d_in, const int* in_sizes, int n_in,
                              void* d_out, int out_size, void* d_ws, size_t ws_size,
                              hipStream_t stream) {
    const float* Hm = (const float*)d_in[0];
    const float* Av = (const float*)d_in[1];
    const float* W1 = (const float*)d_in[2];
    const float* b1 = (const float*)d_in[3];
    const float* W2 = (const float*)d_in[4];
    const float* b2 = (const float*)d_in[5];
    const int*   Ar = (const int*)d_in[6];
    const int*   Ac = (const int*)d_in[7];
    float*       out = (float*)d_out;

    const int N   = in_sizes[0] / DD;
    const int NNZ = in_sizes[6];

    // workspace layout (4-byte elements)
    char* ws = (char*)d_ws;
    size_t off = 0;
    float* X1 = (float*)(ws + off); off += (size_t)N * HH * 4;
    float* S1 = (float*)(ws + off); off += (size_t)N * HH * 4;
    float* T  = (float*)(ws + off); off += (size_t)N * HH * 4;
    int* cnt       = (int*)(ws + off); off += (size_t)N * 4;
    int* incl      = (int*)(ws + off); off += (size_t)N * 4;
    int* bsum      = (int*)(ws + off); off += 512 * 4;
    int* row_start = (int*)(ws + off); off += (size_t)(N + 1) * 4;
    int* cursor    = (int*)(ws + off); off += (size_t)N * 4;
    int* ecol      = (int*)(ws + off); off += (size_t)NNZ * 4;
    float* eval    = (float*)(ws + off); off += (size_t)NNZ * 4;
    const bool csr_ok = (off <= ws_size);

    // K1: X1 = H @ W1
    k_gemm1<<<(N + 63) / 64, 64, 0, stream>>>(Hm, W1, X1, N);

    const int gE = (NNZ + 255) / 256;        // edge-parallel grid
    const int gR = (N + 255) / 256;          // row-parallel grid
    const int nscan = gR;                    // scan blocks over N

    if (csr_ok) {
        // --- build CSR (every call) ---
        hipMemsetAsync(cnt, 0, (size_t)N * 4, stream);
        k_hist<<<gE, 256, 0, stream>>>(Ar, cnt, NNZ);
        k_scan1<<<nscan, 256, 0, stream>>>(cnt, incl, bsum, N);
        k_scan2<<<1, 512, 0, stream>>>(bsum, nscan);
        k_scan3<<<nscan, 256, 0, stream>>>(incl, bsum, cnt, row_start, cursor, N);
        k_scatter<<<gE, 256, 0, stream>>>(Ar, Ac, Av, cursor, ecol, eval, NNZ);

        // --- two gather spmms, no output atomics ---
        int gG = ((size_t)N * HH + 255) / 256;
        k_gather<0><<<gG, 256, 0, stream>>>(row_start, ecol, eval, X1, S1, b1, N);
        k_gather<1><<<gG, 256, 0, stream>>>(row_start, ecol, eval, S1, T, b1, N);
    } else {
        // --- fallback: scatter atomics ---
        hipMemsetAsync(S1, 0, (size_t)2 * N * HH * 4, stream);  // S1 and T adjacent
        long long work = (long long)NNZ * HH;
        int g2 = (int)((work + 255) / 256);
        k_spmm<<<g2, 256, 0, stream>>>(Ar, Ac, Av, X1, S1, b1, 0, NNZ);
        k_spmm<<<g2, 256, 0, stream>>>(Ar, Ac, Av, S1, T, b1, 1, NNZ);
    }

    // K4: out = log_softmax(relu(T @ W2 + b2))
    k_out<<<gR, 256, 0, stream>>>(T, W2, b2, out, N);
}